// Round 4
// baseline (601.545 us; speedup 1.0000x reference)
//
#include <hip/hip_runtime.h>
#include <type_traits>

// LSTMNet: B=1024, T=2048, H=64, NC=10, input_size=1.
// R18: (a) compact 4-row A-exchange layout, (b) sched_group_barrier interleave.
//  - R17 post-mortem: 33 conflict-cy/block-step are the h ds_write (quad
//    stride 64B = 16 banks: quads {0,2}/{1,3} alias -> ~8-phase b16 write).
//    MFMA A-rows are independent, and we only read D rows 4q -> rows 1-3,
//    5-7,... may be GARBAGE. So store only 4 real rows:
//      addr(kt,kq,q,j) = kt*168 + kq*40 + q*8 + j   (shorts; j = unit&7)
//    Write: 8 groups at banks {20kq+4q}%32, 8 lanes x 2B in 4 banks each
//    (2/dword = free) -> ~2 phases (was ~8). Read: lane l -> kq=l>>4,
//    row'=(l>>2)&3: 4-way same-address broadcast, 256B distinct (was 1024B)
//    -> ~3 phases. Lanes with A-row%4!=0 read aliased rows = garbage D rows,
//    never read back. 80B/16B strides keep ds_read_b128 16B-aligned.
//  - R17's source-order MFMA interleave was a no-op (compiler rescheduls).
//    Enforce with sched_group_barrier: DS reads, then per-gate MFMA pairs
//    (f,g,i,o) with small VALU groups between -> cc-chain starts ~100cy
//    earlier. If this regresses, revert the SGB block only.
// Precision: identical math to R17 (absmax 9.8e-4 measured).

#define T_STEPS 2048
#define HID 64
#define NCLS 10
#define XCH 128   // x chunk length (steps)
#define ROWS 4    // batch rows per block

#define KQS 40    // kq stride in shorts (80B = 20 banks, 16B-aligned)
#define KTS 168   // kt stride in shorts (4*KQS + 8 pad; 336B, 16B-aligned)

typedef short bf16x8 __attribute__((ext_vector_type(8)));
typedef float f32x4 __attribute__((ext_vector_type(4)));

__device__ __forceinline__ unsigned short f2bf(float f) {  // RNE f32->bf16
    unsigned u = __builtin_bit_cast(unsigned, f);
    u = u + 0x7FFFu + ((u >> 16) & 1u);
    return (unsigned short)(u >> 16);
}

__global__ __attribute__((amdgpu_flat_work_group_size(256, 256)))
void lstm_mfma_kernel(
    const float* __restrict__ x,      // [B, 1, T]
    const float* __restrict__ W_ih,   // [256, 1]
    const float* __restrict__ W_hh,   // [256, 64]
    const float* __restrict__ b_ih,   // [256]
    const float* __restrict__ b_hh,   // [256]
    const float* __restrict__ fc1_w,  // [64, 64]
    const float* __restrict__ fc1_b,  // [64]
    const float* __restrict__ fc2_w,  // [10, 64]
    const float* __restrict__ fc2_b,  // [10]
    float* __restrict__ out)          // [B, 10]
{
    const int tid  = threadIdx.x;
    const int lane = tid & 63;
    const int w    = tid >> 6;        // wave id = unit-chunk owner
    const int quad = lane >> 4;       // = batch row within block (D-row 4*quad)
    const int col  = lane & 15;
    const int row0 = blockIdx.x * ROWS;

    const float L2E = 1.4426950408889634f;

    // ---- LDS union: 32KB staging (dead after B-frag load) overlaps runtime ----
    __shared__ __align__(16) char smem[32768];
    short* whi = (short*)smem;                 // staging [0,32768)
    // runtime (valid only after the staging->register handoff sync):
    short (*abuf)[2 * KTS]     = (short(*)[2 * KTS])smem;           // 1344 B
    float (*xlds)[XCH + 4]     = (float(*)[XCH + 4])(smem + 1344);  // 2112 B
    float (*hf)[HID + 1]       = (float(*)[HID + 1])(smem + 3456);  // 1040 B
    float (*r1buf)[HID + 1]    = (float(*)[HID + 1])(smem + 4496);  // 1040 B

    // ---- stage: W_hh f32 -> bf16 fragments, pre-scaled per gate ----
    // tile t_ = g*4 + u4  => wave w (reading t_ = gg*4 + w) gets all 4 gates
    // for units 16w..16w+15. (B-layout unchanged from R15.)
    for (int idx = tid; idx < 256 * 64; idx += 256) {
        int r_ = idx >> 6;            // gate-major row 0..255
        int k  = idx & 63;
        int g = r_ >> 6, u = r_ & 63;
        float scg = (g == 2) ? -2.0f * L2E : -L2E;
        float f = W_hh[r_ * 64 + k] * scg;
        int u4 = u >> 4, n = u & 15;
        int kt = k >> 5, kq = (k & 31) >> 3, j = k & 7;
        int off = (((g * 4 + u4) * 2 + kt) * 64 + (kq * 16 + n)) * 8 + j;
        whi[off] = (short)f2bf(f);
    }
    __syncthreads();

    // ---- B fragments -> registers (wave w: tiles t_ = gg*4 + w) ----
    const int u0 = w * 16 + col;      // this lane's unit (cols of all 4 tiles)
    bf16x8 Bq[4][2];
    f32x4 biasC[4];
    f32x4 zerov = {0.f, 0.f, 0.f, 0.f};
    #pragma unroll
    for (int gg = 0; gg < 4; ++gg) {
        int t_ = gg * 4 + w;
        #pragma unroll
        for (int kt = 0; kt < 2; ++kt) {
            int off = ((t_ * 2 + kt) * 64 + lane) * 8;
            Bq[gg][kt] = *(const bf16x8*)&whi[off];
            asm volatile("" : "+v"(Bq[gg][kt]));
        }
        float scg = (gg == 2) ? -2.0f * L2E : -L2E;
        float bs = (b_ih[gg * HID + u0] + b_hh[gg * HID + u0]) * scg;
        #pragma unroll
        for (int r = 0; r < 4; ++r) biasC[gg][r] = bs;
    }
    __syncthreads();   // all waves done READING staging; smem may be reused now

    // zero BOTH A buffers (h0 = 0)
    for (int idx = tid; idx < 2 * 2 * KTS; idx += 256) ((short*)abuf)[idx] = 0;

    // ---- update constants: quad q owns cell (batch row q, unit u0) ----
    float wih_u[4];
    #pragma unroll
    for (int gg = 0; gg < 4; ++gg) {
        float scg = (gg == 2) ? -2.0f * L2E : -L2E;
        wih_u[gg] = W_ih[gg * HID + u0] * scg;
    }
    float ccs = 0.f, hl = 0.f;   // ccs = -2log2e * c  (pre-scaled cell state)

    // invariant LDS coords (compact layout)
    // read: lane l -> kq = l>>4, row' = (l>>2)&3 (valid for A-rows 4*row';
    //        other lanes alias -> garbage D rows, never read)
    const int ard0 = (lane >> 4) * KQS + ((lane >> 2) & 3) * 8;   // kt1 at +KTS
    // write: h(batch quad, unit u0) at (kt=u0>>5, kq=(u0>>3)&3, q=quad, j=u0&7)
    const int awr  = (u0 >> 5) * KTS + ((u0 >> 3) & 3) * KQS + quad * 8 + (u0 & 7);

    const float* xbase = x + (size_t)row0 * T_STEPS;
    __syncthreads();   // abuf zeroed

    auto step = [&](auto cur_c, int tl) __attribute__((always_inline)) {
        constexpr int CUR = decltype(cur_c)::value;
        constexpr int NXT = CUR ^ 1;

        // issue all LDS reads up front: A-frags + this step's x
        bf16x8 A0 = *(const bf16x8*)&abuf[CUR][ard0];
        bf16x8 A1 = *(const bf16x8*)&abuf[CUR][ard0 + KTS];
        float xv = xlds[quad][tl];

        // ---- per-gate MFMA pairs, order f, g, i, o; kt-parallel in pair ----
        f32x4 fl = __builtin_amdgcn_mfma_f32_16x16x32_bf16(A0, Bq[1][0], biasC[1], 0, 0, 0);
        f32x4 fh = __builtin_amdgcn_mfma_f32_16x16x32_bf16(A1, Bq[1][1], zerov,   0, 0, 0);
        f32x4 gl = __builtin_amdgcn_mfma_f32_16x16x32_bf16(A0, Bq[2][0], biasC[2], 0, 0, 0);
        f32x4 gh = __builtin_amdgcn_mfma_f32_16x16x32_bf16(A1, Bq[2][1], zerov,   0, 0, 0);
        f32x4 il = __builtin_amdgcn_mfma_f32_16x16x32_bf16(A0, Bq[0][0], biasC[0], 0, 0, 0);
        f32x4 ih = __builtin_amdgcn_mfma_f32_16x16x32_bf16(A1, Bq[0][1], zerov,   0, 0, 0);
        f32x4 ol = __builtin_amdgcn_mfma_f32_16x16x32_bf16(A0, Bq[3][0], biasC[3], 0, 0, 0);
        f32x4 oh = __builtin_amdgcn_mfma_f32_16x16x32_bf16(A1, Bq[3][1], zerov,   0, 0, 0);

        // ---- fused update: quad q -> D-row 4q (reg0), ALL 64 lanes active ----
        {
            // f-gate chain (feeds ccs fmaf) starts as soon as its pair lands
            float a1 = fmaf(xv, wih_u[1], fl[0] + fh[0]);
            float fg = __builtin_amdgcn_rcpf(1.0f + __builtin_amdgcn_exp2f(a1));
            // g-gate: gv' = -2L2E*tanh = fmaf(-4L2E, r2, 2L2E)
            float a2 = fmaf(xv, wih_u[2], gl[0] + gh[0]);
            float r2 = __builtin_amdgcn_rcpf(1.0f + __builtin_amdgcn_exp2f(a2));
            float gvs = fmaf(-5.7707801635558536f, r2, 2.8853900817779268f);
            // i-gate
            float a0 = fmaf(xv, wih_u[0], il[0] + ih[0]);
            float ig = __builtin_amdgcn_rcpf(1.0f + __builtin_amdgcn_exp2f(a0));
            float igv = ig * gvs;                 // = -2L2E * i*g~
            ccs = fmaf(fg, ccs, igv);             // ccs = -2L2E * c
            float ec = __builtin_amdgcn_exp2f(ccs);
            float rc = __builtin_amdgcn_rcpf(1.0f + ec);
            // o-gate (off the cc chain; overlaps the rcp waits)
            float a3 = fmaf(xv, wih_u[3], ol[0] + oh[0]);
            float og = __builtin_amdgcn_rcpf(1.0f + __builtin_amdgcn_exp2f(a3));
            float og2 = og + og, ogn = -og;
            hl = fmaf(og2, rc, ogn);              // og * (2rc - 1) = og*tanh(c)
            unsigned hp;
            asm("v_cvt_pk_bf16_f32 %0, %1, %2" : "=v"(hp) : "v"(hl), "v"(hl));
            abuf[NXT][awr] = (short)hp;
        }

        // ---- schedule shaping: DS reads first, then per-gate MFMA pairs with
        // small VALU groups between so the f/g chains overlap MFMA issue ----
        __builtin_amdgcn_sched_group_barrier(0x100, 3, 0); // 2x b128 + x b32
        __builtin_amdgcn_sched_group_barrier(0x008, 2, 0); // f pair
        __builtin_amdgcn_sched_group_barrier(0x002, 3, 0); // add,fma,exp2(f)
        __builtin_amdgcn_sched_group_barrier(0x008, 2, 0); // g pair
        __builtin_amdgcn_sched_group_barrier(0x002, 4, 0); // rcp(f),add,fma,exp2(g)
        __builtin_amdgcn_sched_group_barrier(0x008, 2, 0); // i pair
        __builtin_amdgcn_sched_group_barrier(0x002, 5, 0); // rcp(g),fma,add,fma,exp2(i)
        __builtin_amdgcn_sched_group_barrier(0x008, 2, 0); // o pair
        // remainder (cc chain tail, o chain, cvt, ds_write) unconstrained

        __syncthreads();   // new h-frags visible (single barrier per step)
    };

    #pragma unroll 1
    for (int tc = 0; tc < T_STEPS; tc += 2) {
        const int tl = tc & (XCH - 1);
        if (tl == 0) {
            // refill x chunk: wave w writes row w's consecutive dwords
            {
                int i = lane;
                const float* src = xbase + (size_t)w * T_STEPS + tc;
                xlds[w][i]      = src[i];
                xlds[w][i + 64] = src[i + 64];
            }
            __syncthreads();
        }
        step(std::integral_constant<int, 0>{}, tl);      // reads abuf[0], writes abuf[1]
        step(std::integral_constant<int, 1>{}, tl + 1);  // reads abuf[1], writes abuf[0]
    }

    // ---- epilogue: gather h, fc1 (relu) + fc2 ----
    hf[quad][u0] = hl;   // (row quad, unit 16w+col): 4x64 values, all lanes
    __syncthreads();

    if (w < ROWS) {
        // thread -> (row = w, unit = lane)
        float s = fc1_b[lane];
        const float4* wrow = (const float4*)(fc1_w + lane * HID);
        #pragma unroll
        for (int j4 = 0; j4 < HID / 4; ++j4) {
            float4 wv = wrow[j4];
            s = fmaf(hf[w][j4 * 4 + 0], wv.x, s);
            s = fmaf(hf[w][j4 * 4 + 1], wv.y, s);
            s = fmaf(hf[w][j4 * 4 + 2], wv.z, s);
            s = fmaf(hf[w][j4 * 4 + 3], wv.w, s);
        }
        r1buf[w][lane] = fmaxf(s, 0.0f);
    }
    __syncthreads();

    if (tid < ROWS * NCLS) {
        int m = tid / NCLS, cls = tid % NCLS;
        float s = fc2_b[cls];
        const float* w2 = fc2_w + cls * HID;
        #pragma unroll
        for (int j = 0; j < HID; ++j) s = fmaf(r1buf[m][j], w2[j], s);
        out[(size_t)(row0 + m) * NCLS + cls] = s;
    }
}

extern "C" void kernel_launch(void* const* d_in, const int* in_sizes, int n_in,
                              void* d_out, int out_size, void* d_ws, size_t ws_size,
                              hipStream_t stream) {
    const float* x     = (const float*)d_in[0];
    const float* W_ih  = (const float*)d_in[1];
    const float* W_hh  = (const float*)d_in[2];
    const float* b_ih  = (const float*)d_in[3];
    const float* b_hh  = (const float*)d_in[4];
    const float* fc1_w = (const float*)d_in[5];
    const float* fc1_b = (const float*)d_in[6];
    const float* fc2_w = (const float*)d_in[7];
    const float* fc2_b = (const float*)d_in[8];
    float* out = (float*)d_out;

    dim3 grid(256);   // 1024 rows / 4 rows per block -> 1 block per CU
    dim3 block(256);  // 4 waves (1 per SIMD)
    lstm_mfma_kernel<<<grid, block, 0, stream>>>(x, W_ih, W_hh, b_ih, b_hh,
                                                 fc1_w, fc1_b, fc2_w, fc2_b, out);
}

// Round 6
// 547.048 us; speedup vs baseline: 1.0996x; 1.0996x over previous
//
#include <hip/hip_runtime.h>
#include <type_traits>

// LSTMNet: B=1024, T=2048, H=64, NC=10, input_size=1.
// R19 (resubmit; prior attempt hit container-infra failure, no signal):
// R18 minus the sched_group_barrier block (SGB was -50us: forced
// schedule stalled both pipes; MfmaUtil 21.7->19.4, VALUBusy 38.5->34.4).
// Keeps R18's compact 4-row A-exchange layout, which was a verified win:
// SQ_LDS_BANK_CONFLICT 1.72e7 -> 3.95e5 (43x).
//  - A layout: addr(kt,kq,q,j) = kt*168 + kq*40 + q*8 + j (shorts).
//    Write ~2-phase, read ~3-phase w/ 4-way broadcast. MFMA D rows != 4q
//    receive garbage (aliased A rows) and are never read.
//  - Per-gate kt-parallel MFMA pairs in source order f,g,i,o; compiler
//    schedules freely (R17-measured-best arrangement).
//  - Pre-scaled cell state ccs = -2log2e*c; scales folded into W/bias.
// Precision: identical math to R17/R18 (absmax 9.8e-4 measured).

#define T_STEPS 2048
#define HID 64
#define NCLS 10
#define XCH 128   // x chunk length (steps)
#define ROWS 4    // batch rows per block

#define KQS 40    // kq stride in shorts (80B = 20 banks, 16B-aligned)
#define KTS 168   // kt stride in shorts (4*KQS + 8 pad; 336B, 16B-aligned)

typedef short bf16x8 __attribute__((ext_vector_type(8)));
typedef float f32x4 __attribute__((ext_vector_type(4)));

__device__ __forceinline__ unsigned short f2bf(float f) {  // RNE f32->bf16
    unsigned u = __builtin_bit_cast(unsigned, f);
    u = u + 0x7FFFu + ((u >> 16) & 1u);
    return (unsigned short)(u >> 16);
}

__global__ __attribute__((amdgpu_flat_work_group_size(256, 256)))
void lstm_mfma_kernel(
    const float* __restrict__ x,      // [B, 1, T]
    const float* __restrict__ W_ih,   // [256, 1]
    const float* __restrict__ W_hh,   // [256, 64]
    const float* __restrict__ b_ih,   // [256]
    const float* __restrict__ b_hh,   // [256]
    const float* __restrict__ fc1_w,  // [64, 64]
    const float* __restrict__ fc1_b,  // [64]
    const float* __restrict__ fc2_w,  // [10, 64]
    const float* __restrict__ fc2_b,  // [10]
    float* __restrict__ out)          // [B, 10]
{
    const int tid  = threadIdx.x;
    const int lane = tid & 63;
    const int w    = tid >> 6;        // wave id = unit-chunk owner
    const int quad = lane >> 4;       // = batch row within block (D-row 4*quad)
    const int col  = lane & 15;
    const int row0 = blockIdx.x * ROWS;

    const float L2E = 1.4426950408889634f;

    // ---- LDS union: 32KB staging (dead after B-frag load) overlaps runtime ----
    __shared__ __align__(16) char smem[32768];
    short* whi = (short*)smem;                 // staging [0,32768)
    // runtime (valid only after the staging->register handoff sync):
    short (*abuf)[2 * KTS]     = (short(*)[2 * KTS])smem;           // 1344 B
    float (*xlds)[XCH + 4]     = (float(*)[XCH + 4])(smem + 1344);  // 2112 B
    float (*hf)[HID + 1]       = (float(*)[HID + 1])(smem + 3456);  // 1040 B
    float (*r1buf)[HID + 1]    = (float(*)[HID + 1])(smem + 4496);  // 1040 B

    // ---- stage: W_hh f32 -> bf16 fragments, pre-scaled per gate ----
    // tile t_ = g*4 + u4  => wave w (reading t_ = gg*4 + w) gets all 4 gates
    // for units 16w..16w+15. (B-layout unchanged from R15.)
    for (int idx = tid; idx < 256 * 64; idx += 256) {
        int r_ = idx >> 6;            // gate-major row 0..255
        int k  = idx & 63;
        int g = r_ >> 6, u = r_ & 63;
        float scg = (g == 2) ? -2.0f * L2E : -L2E;
        float f = W_hh[r_ * 64 + k] * scg;
        int u4 = u >> 4, n = u & 15;
        int kt = k >> 5, kq = (k & 31) >> 3, j = k & 7;
        int off = (((g * 4 + u4) * 2 + kt) * 64 + (kq * 16 + n)) * 8 + j;
        whi[off] = (short)f2bf(f);
    }
    __syncthreads();

    // ---- B fragments -> registers (wave w: tiles t_ = gg*4 + w) ----
    const int u0 = w * 16 + col;      // this lane's unit (cols of all 4 tiles)
    bf16x8 Bq[4][2];
    f32x4 biasC[4];
    f32x4 zerov = {0.f, 0.f, 0.f, 0.f};
    #pragma unroll
    for (int gg = 0; gg < 4; ++gg) {
        int t_ = gg * 4 + w;
        #pragma unroll
        for (int kt = 0; kt < 2; ++kt) {
            int off = ((t_ * 2 + kt) * 64 + lane) * 8;
            Bq[gg][kt] = *(const bf16x8*)&whi[off];
            asm volatile("" : "+v"(Bq[gg][kt]));
        }
        float scg = (gg == 2) ? -2.0f * L2E : -L2E;
        float bs = (b_ih[gg * HID + u0] + b_hh[gg * HID + u0]) * scg;
        #pragma unroll
        for (int r = 0; r < 4; ++r) biasC[gg][r] = bs;
    }
    __syncthreads();   // all waves done READING staging; smem may be reused now

    // zero BOTH A buffers (h0 = 0)
    for (int idx = tid; idx < 2 * 2 * KTS; idx += 256) ((short*)abuf)[idx] = 0;

    // ---- update constants: quad q owns cell (batch row q, unit u0) ----
    float wih_u[4];
    #pragma unroll
    for (int gg = 0; gg < 4; ++gg) {
        float scg = (gg == 2) ? -2.0f * L2E : -L2E;
        wih_u[gg] = W_ih[gg * HID + u0] * scg;
    }
    float ccs = 0.f, hl = 0.f;   // ccs = -2log2e * c  (pre-scaled cell state)

    // invariant LDS coords (compact layout)
    // read: lane l -> kq = l>>4, row' = (l>>2)&3 (valid for A-rows 4*row';
    //        other lanes alias -> garbage D rows, never read)
    const int ard0 = (lane >> 4) * KQS + ((lane >> 2) & 3) * 8;   // kt1 at +KTS
    // write: h(batch quad, unit u0) at (kt=u0>>5, kq=(u0>>3)&3, q=quad, j=u0&7)
    const int awr  = (u0 >> 5) * KTS + ((u0 >> 3) & 3) * KQS + quad * 8 + (u0 & 7);

    const float* xbase = x + (size_t)row0 * T_STEPS;
    __syncthreads();   // abuf zeroed

    auto step = [&](auto cur_c, int tl) __attribute__((always_inline)) {
        constexpr int CUR = decltype(cur_c)::value;
        constexpr int NXT = CUR ^ 1;

        // issue all LDS reads up front: A-frags + this step's x
        bf16x8 A0 = *(const bf16x8*)&abuf[CUR][ard0];
        bf16x8 A1 = *(const bf16x8*)&abuf[CUR][ard0 + KTS];
        float xv = xlds[quad][tl];

        // ---- per-gate MFMA pairs, order f, g, i, o; kt-parallel in pair ----
        f32x4 fl = __builtin_amdgcn_mfma_f32_16x16x32_bf16(A0, Bq[1][0], biasC[1], 0, 0, 0);
        f32x4 fh = __builtin_amdgcn_mfma_f32_16x16x32_bf16(A1, Bq[1][1], zerov,   0, 0, 0);
        f32x4 gl = __builtin_amdgcn_mfma_f32_16x16x32_bf16(A0, Bq[2][0], biasC[2], 0, 0, 0);
        f32x4 gh = __builtin_amdgcn_mfma_f32_16x16x32_bf16(A1, Bq[2][1], zerov,   0, 0, 0);
        f32x4 il = __builtin_amdgcn_mfma_f32_16x16x32_bf16(A0, Bq[0][0], biasC[0], 0, 0, 0);
        f32x4 ih = __builtin_amdgcn_mfma_f32_16x16x32_bf16(A1, Bq[0][1], zerov,   0, 0, 0);
        f32x4 ol = __builtin_amdgcn_mfma_f32_16x16x32_bf16(A0, Bq[3][0], biasC[3], 0, 0, 0);
        f32x4 oh = __builtin_amdgcn_mfma_f32_16x16x32_bf16(A1, Bq[3][1], zerov,   0, 0, 0);

        // ---- fused update: quad q -> D-row 4q (reg0), ALL 64 lanes active ----
        {
            // f-gate chain (feeds ccs fmaf) starts as soon as its pair lands
            float a1 = fmaf(xv, wih_u[1], fl[0] + fh[0]);
            float fg = __builtin_amdgcn_rcpf(1.0f + __builtin_amdgcn_exp2f(a1));
            // g-gate: gv' = -2L2E*tanh = fmaf(-4L2E, r2, 2L2E)
            float a2 = fmaf(xv, wih_u[2], gl[0] + gh[0]);
            float r2 = __builtin_amdgcn_rcpf(1.0f + __builtin_amdgcn_exp2f(a2));
            float gvs = fmaf(-5.7707801635558536f, r2, 2.8853900817779268f);
            // i-gate
            float a0 = fmaf(xv, wih_u[0], il[0] + ih[0]);
            float ig = __builtin_amdgcn_rcpf(1.0f + __builtin_amdgcn_exp2f(a0));
            float igv = ig * gvs;                 // = -2L2E * i*g~
            ccs = fmaf(fg, ccs, igv);             // ccs = -2L2E * c
            float ec = __builtin_amdgcn_exp2f(ccs);
            float rc = __builtin_amdgcn_rcpf(1.0f + ec);
            // o-gate (off the cc chain; overlaps the rcp waits)
            float a3 = fmaf(xv, wih_u[3], ol[0] + oh[0]);
            float og = __builtin_amdgcn_rcpf(1.0f + __builtin_amdgcn_exp2f(a3));
            float og2 = og + og, ogn = -og;
            hl = fmaf(og2, rc, ogn);              // og * (2rc - 1) = og*tanh(c)
            unsigned hp;
            asm("v_cvt_pk_bf16_f32 %0, %1, %2" : "=v"(hp) : "v"(hl), "v"(hl));
            abuf[NXT][awr] = (short)hp;
        }
        __syncthreads();   // new h-frags visible (single barrier per step)
    };

    #pragma unroll 1
    for (int tc = 0; tc < T_STEPS; tc += 2) {
        const int tl = tc & (XCH - 1);
        if (tl == 0) {
            // refill x chunk: wave w writes row w's consecutive dwords
            {
                int i = lane;
                const float* src = xbase + (size_t)w * T_STEPS + tc;
                xlds[w][i]      = src[i];
                xlds[w][i + 64] = src[i + 64];
            }
            __syncthreads();
        }
        step(std::integral_constant<int, 0>{}, tl);      // reads abuf[0], writes abuf[1]
        step(std::integral_constant<int, 1>{}, tl + 1);  // reads abuf[1], writes abuf[0]
    }

    // ---- epilogue: gather h, fc1 (relu) + fc2 ----
    hf[quad][u0] = hl;   // (row quad, unit 16w+col): 4x64 values, all lanes
    __syncthreads();

    if (w < ROWS) {
        // thread -> (row = w, unit = lane)
        float s = fc1_b[lane];
        const float4* wrow = (const float4*)(fc1_w + lane * HID);
        #pragma unroll
        for (int j4 = 0; j4 < HID / 4; ++j4) {
            float4 wv = wrow[j4];
            s = fmaf(hf[w][j4 * 4 + 0], wv.x, s);
            s = fmaf(hf[w][j4 * 4 + 1], wv.y, s);
            s = fmaf(hf[w][j4 * 4 + 2], wv.z, s);
            s = fmaf(hf[w][j4 * 4 + 3], wv.w, s);
        }
        r1buf[w][lane] = fmaxf(s, 0.0f);
    }
    __syncthreads();

    if (tid < ROWS * NCLS) {
        int m = tid / NCLS, cls = tid % NCLS;
        float s = fc2_b[cls];
        const float* w2 = fc2_w + cls * HID;
        #pragma unroll
        for (int j = 0; j < HID; ++j) s = fmaf(r1buf[m][j], w2[j], s);
        out[(size_t)(row0 + m) * NCLS + cls] = s;
    }
}

extern "C" void kernel_launch(void* const* d_in, const int* in_sizes, int n_in,
                              void* d_out, int out_size, void* d_ws, size_t ws_size,
                              hipStream_t stream) {
    const float* x     = (const float*)d_in[0];
    const float* W_ih  = (const float*)d_in[1];
    const float* W_hh  = (const float*)d_in[2];
    const float* b_ih  = (const float*)d_in[3];
    const float* b_hh  = (const float*)d_in[4];
    const float* fc1_w = (const float*)d_in[5];
    const float* fc1_b = (const float*)d_in[6];
    const float* fc2_w = (const float*)d_in[7];
    const float* fc2_b = (const float*)d_in[8];
    float* out = (float*)d_out;

    dim3 grid(256);   // 1024 rows / 4 rows per block -> 1 block per CU
    dim3 block(256);  // 4 waves (1 per SIMD)
    lstm_mfma_kernel<<<grid, block, 0, stream>>>(x, W_ih, W_hh, b_ih, b_hh,
                                                 fc1_w, fc1_b, fc2_w, fc2_b, out);
}

// Round 7
// 543.764 us; speedup vs baseline: 1.1063x; 1.0060x over previous
//
#include <hip/hip_runtime.h>
#include <type_traits>

// LSTMNet: B=1024, T=2048, H=64, NC=10, input_size=1.
// R20: recombination of the two measured-best components:
//  - STEP BODY: exactly R16's (522 us, best measured): MFMA source order
//    all-lo(bias) then all-hi(zero) in gate order i,f,g,o; simple update
//    chain (unscaled cc, scale applied inside exp2). R17's "surgery"
//    reordering was a measured -12us regression; compiler schedules best
//    from R16's source (same lesson as the SGB -50us: don't fight the
//    scheduler on this codegen).
//  - A-EXCHANGE LAYOUT: R18/R19's compact 4-row layout (verified:
//    SQ_LDS_BANK_CONFLICT 1.72e7 -> 3.95e5, -5us):
//      addr(kt,kq,q,j) = kt*168 + kq*40 + q*8 + j (shorts)
//    MFMA D rows != 4q receive garbage (aliased A rows), never read.
// Structure: 256 blocks x 4 waves, ROWS=4 (quad q = batch row q -> D row 4q,
// reg0), fused gate+update in one wave, 1 barrier + 1 LDS round trip/step.
// Precision: bit-identical to R16 (absmax 9.77e-4 measured).

#define T_STEPS 2048
#define HID 64
#define NCLS 10
#define XCH 128   // x chunk length (steps)
#define ROWS 4    // batch rows per block

#define KQS 40    // kq stride in shorts (80B = 20 banks, 16B-aligned)
#define KTS 168   // kt stride in shorts (4*KQS + 8 pad; 336B, 16B-aligned)

typedef short bf16x8 __attribute__((ext_vector_type(8)));
typedef float f32x4 __attribute__((ext_vector_type(4)));

__device__ __forceinline__ unsigned short f2bf(float f) {  // RNE f32->bf16
    unsigned u = __builtin_bit_cast(unsigned, f);
    u = u + 0x7FFFu + ((u >> 16) & 1u);
    return (unsigned short)(u >> 16);
}

__global__ __attribute__((amdgpu_flat_work_group_size(256, 256)))
void lstm_mfma_kernel(
    const float* __restrict__ x,      // [B, 1, T]
    const float* __restrict__ W_ih,   // [256, 1]
    const float* __restrict__ W_hh,   // [256, 64]
    const float* __restrict__ b_ih,   // [256]
    const float* __restrict__ b_hh,   // [256]
    const float* __restrict__ fc1_w,  // [64, 64]
    const float* __restrict__ fc1_b,  // [64]
    const float* __restrict__ fc2_w,  // [10, 64]
    const float* __restrict__ fc2_b,  // [10]
    float* __restrict__ out)          // [B, 10]
{
    const int tid  = threadIdx.x;
    const int lane = tid & 63;
    const int w    = tid >> 6;        // wave id = unit-chunk owner
    const int quad = lane >> 4;       // = batch row within block (D-row 4*quad)
    const int col  = lane & 15;
    const int row0 = blockIdx.x * ROWS;

    const float L2E = 1.4426950408889634f;

    // ---- LDS union: 32KB staging (dead after B-frag load) overlaps runtime ----
    __shared__ __align__(16) char smem[32768];
    short* whi = (short*)smem;                 // staging [0,32768)
    // runtime (valid only after the staging->register handoff sync):
    short (*abuf)[2 * KTS]     = (short(*)[2 * KTS])smem;           // 1344 B
    float (*xlds)[XCH + 4]     = (float(*)[XCH + 4])(smem + 1344);  // 2112 B
    float (*hf)[HID + 1]       = (float(*)[HID + 1])(smem + 3456);  // 1040 B
    float (*r1buf)[HID + 1]    = (float(*)[HID + 1])(smem + 4496);  // 1040 B

    // ---- stage: W_hh f32 -> bf16 fragments, pre-scaled per gate ----
    // tile t_ = g*4 + u4  => wave w (reading t_ = gg*4 + w) gets all 4 gates
    // for units 16w..16w+15. (B-layout unchanged from R15.)
    for (int idx = tid; idx < 256 * 64; idx += 256) {
        int r_ = idx >> 6;            // gate-major row 0..255
        int k  = idx & 63;
        int g = r_ >> 6, u = r_ & 63;
        float scg = (g == 2) ? -2.0f * L2E : -L2E;
        float f = W_hh[r_ * 64 + k] * scg;
        int u4 = u >> 4, n = u & 15;
        int kt = k >> 5, kq = (k & 31) >> 3, j = k & 7;
        int off = (((g * 4 + u4) * 2 + kt) * 64 + (kq * 16 + n)) * 8 + j;
        whi[off] = (short)f2bf(f);
    }
    __syncthreads();

    // ---- B fragments -> registers (wave w: tiles t_ = gg*4 + w) ----
    const int u0 = w * 16 + col;      // this lane's unit (cols of all 4 tiles)
    bf16x8 Bq[4][2];
    f32x4 biasC[4];
    f32x4 zerov = {0.f, 0.f, 0.f, 0.f};
    #pragma unroll
    for (int gg = 0; gg < 4; ++gg) {
        int t_ = gg * 4 + w;
        #pragma unroll
        for (int kt = 0; kt < 2; ++kt) {
            int off = ((t_ * 2 + kt) * 64 + lane) * 8;
            Bq[gg][kt] = *(const bf16x8*)&whi[off];
            asm volatile("" : "+v"(Bq[gg][kt]));
        }
        float scg = (gg == 2) ? -2.0f * L2E : -L2E;
        float bs = (b_ih[gg * HID + u0] + b_hh[gg * HID + u0]) * scg;
        #pragma unroll
        for (int r = 0; r < 4; ++r) biasC[gg][r] = bs;
    }
    __syncthreads();   // all waves done READING staging; smem may be reused now

    // zero BOTH A buffers (h0 = 0)
    for (int idx = tid; idx < 2 * 2 * KTS; idx += 256) ((short*)abuf)[idx] = 0;

    // ---- update constants: quad q owns cell (batch row q, unit u0) ----
    float wih_u[4];
    #pragma unroll
    for (int gg = 0; gg < 4; ++gg) {
        float scg = (gg == 2) ? -2.0f * L2E : -L2E;
        wih_u[gg] = W_ih[gg * HID + u0] * scg;
    }
    float cc = 0.f, hl = 0.f;

    // invariant LDS coords (compact layout)
    // read: lane l -> kq = l>>4, row' = (l>>2)&3 (valid for A-rows 4*row';
    //        other lanes alias -> garbage D rows, never read)
    const int ard0 = (lane >> 4) * KQS + ((lane >> 2) & 3) * 8;   // kt1 at +KTS
    // write: h(batch quad, unit u0) at (kt=u0>>5, kq=(u0>>3)&3, q=quad, j=u0&7)
    const int awr  = (u0 >> 5) * KTS + ((u0 >> 3) & 3) * KQS + quad * 8 + (u0 & 7);

    const float* xbase = x + (size_t)row0 * T_STEPS;
    __syncthreads();   // abuf zeroed

    auto step = [&](auto cur_c, int tl) __attribute__((always_inline)) {
        constexpr int CUR = decltype(cur_c)::value;
        constexpr int NXT = CUR ^ 1;

        // ---- all 4 gates for units 16w..16w+15, rows {0,4,8,12} ----
        bf16x8 A0 = *(const bf16x8*)&abuf[CUR][ard0];
        bf16x8 A1 = *(const bf16x8*)&abuf[CUR][ard0 + KTS];

        // kt-parallel: two independent MFMAs, combine reg0 with one add
        // (R16 source order: all lo, then all hi; gate order i,f,g,o)
        f32x4 alo[4], ahi[4];
        #pragma unroll
        for (int gg = 0; gg < 4; ++gg)
            alo[gg] = __builtin_amdgcn_mfma_f32_16x16x32_bf16(A0, Bq[gg][0], biasC[gg], 0, 0, 0);
        #pragma unroll
        for (int gg = 0; gg < 4; ++gg)
            ahi[gg] = __builtin_amdgcn_mfma_f32_16x16x32_bf16(A1, Bq[gg][1], zerov, 0, 0, 0);

        // ---- fused update: quad q -> D-row 4q (reg0), ALL 64 lanes active ----
        {
            float xv = xlds[quad][tl];
            // pre-scaled args: sigm gates hold -log2e*a, tanh gate -2log2e*a
            float a0 = fmaf(xv, wih_u[0], alo[0][0] + ahi[0][0]);
            float a1 = fmaf(xv, wih_u[1], alo[1][0] + ahi[1][0]);
            float a2 = fmaf(xv, wih_u[2], alo[2][0] + ahi[2][0]);
            float a3 = fmaf(xv, wih_u[3], alo[3][0] + ahi[3][0]);
            float ig = __builtin_amdgcn_rcpf(1.0f + __builtin_amdgcn_exp2f(a0));
            float fg = __builtin_amdgcn_rcpf(1.0f + __builtin_amdgcn_exp2f(a1));
            float gv = fmaf(2.0f, __builtin_amdgcn_rcpf(1.0f + __builtin_amdgcn_exp2f(a2)), -1.0f);
            float og = __builtin_amdgcn_rcpf(1.0f + __builtin_amdgcn_exp2f(a3));
            cc = fmaf(fg, cc, ig * gv);
            float ec = __builtin_amdgcn_exp2f(-2.8853900817779268f * cc);
            float th = fmaf(2.0f, __builtin_amdgcn_rcpf(1.0f + ec), -1.0f);
            hl = og * th;
            unsigned hp;
            asm("v_cvt_pk_bf16_f32 %0, %1, %2" : "=v"(hp) : "v"(hl), "v"(hl));
            abuf[NXT][awr] = (short)hp;
        }
        __syncthreads();   // new h-frags visible (single barrier per step)
    };

    #pragma unroll 1
    for (int tc = 0; tc < T_STEPS; tc += 2) {
        const int tl = tc & (XCH - 1);
        if (tl == 0) {
            // refill x chunk: wave w writes row w's consecutive dwords
            {
                int i = lane;
                const float* src = xbase + (size_t)w * T_STEPS + tc;
                xlds[w][i]      = src[i];
                xlds[w][i + 64] = src[i + 64];
            }
            __syncthreads();
        }
        step(std::integral_constant<int, 0>{}, tl);      // reads abuf[0], writes abuf[1]
        step(std::integral_constant<int, 1>{}, tl + 1);  // reads abuf[1], writes abuf[0]
    }

    // ---- epilogue: gather h, fc1 (relu) + fc2 ----
    hf[quad][u0] = hl;   // (row quad, unit 16w+col): 4x64 values, all lanes
    __syncthreads();

    if (w < ROWS) {
        // thread -> (row = w, unit = lane)
        float s = fc1_b[lane];
        const float4* wrow = (const float4*)(fc1_w + lane * HID);
        #pragma unroll
        for (int j4 = 0; j4 < HID / 4; ++j4) {
            float4 wv = wrow[j4];
            s = fmaf(hf[w][j4 * 4 + 0], wv.x, s);
            s = fmaf(hf[w][j4 * 4 + 1], wv.y, s);
            s = fmaf(hf[w][j4 * 4 + 2], wv.z, s);
            s = fmaf(hf[w][j4 * 4 + 3], wv.w, s);
        }
        r1buf[w][lane] = fmaxf(s, 0.0f);
    }
    __syncthreads();

    if (tid < ROWS * NCLS) {
        int m = tid / NCLS, cls = tid % NCLS;
        float s = fc2_b[cls];
        const float* w2 = fc2_w + cls * HID;
        #pragma unroll
        for (int j = 0; j < HID; ++j) s = fmaf(r1buf[m][j], w2[j], s);
        out[(size_t)(row0 + m) * NCLS + cls] = s;
    }
}

extern "C" void kernel_launch(void* const* d_in, const int* in_sizes, int n_in,
                              void* d_out, int out_size, void* d_ws, size_t ws_size,
                              hipStream_t stream) {
    const float* x     = (const float*)d_in[0];
    const float* W_ih  = (const float*)d_in[1];
    const float* W_hh  = (const float*)d_in[2];
    const float* b_ih  = (const float*)d_in[3];
    const float* b_hh  = (const float*)d_in[4];
    const float* fc1_w = (const float*)d_in[5];
    const float* fc1_b = (const float*)d_in[6];
    const float* fc2_w = (const float*)d_in[7];
    const float* fc2_b = (const float*)d_in[8];
    float* out = (float*)d_out;

    dim3 grid(256);   // 1024 rows / 4 rows per block -> 1 block per CU
    dim3 block(256);  // 4 waves (1 per SIMD)
    lstm_mfma_kernel<<<grid, block, 0, stream>>>(x, W_ih, W_hh, b_ih, b_hh,
                                                 fc1_w, fc1_b, fc2_w, fc2_b, out);
}